// Round 5
// baseline (193.123 us; speedup 1.0000x reference)
//
#include <hip/hip_runtime.h>

// MMD RBF loss, N=8192, D=128, gamma=1, fp32 in, fp32 scalar out.
// R5: occupancy-overlap regime. 16 KB B-panels (128 rows A x 64 cols B),
// double-buffered in 32 KB LDS -> 4 blocks/CU; stalled blocks are covered by
// the other three (m114 implicit overlap). A-strips in registers per wave.
// dbn loads issued before staging (+ sched_barrier) so their use never
// drains the in-flight prefetch. Thresholded exp epilogue as before.

#define N_PTS 8192
#define TJ 64          // 8192/128 row-tiles per side
#define NSELF 2080     // 64*65/2
#define NJOBS 8256     // 2*2080 + 4096  (128x128 jobs; each = 2 sub-steps)
#define NBLOCKS 1024
#define NWAVES (NBLOCKS * 4)
#define LOG2E 1.4426950408889634f
#define THRESH -40.0f

typedef __attribute__((ext_vector_type(8))) short short8;    // 8 bf16
typedef __attribute__((ext_vector_type(16))) float floatx16; // 32x32 acc
typedef unsigned int u32;
typedef unsigned short u16;

#if __has_builtin(__builtin_amdgcn_exp2f)
#define EXP2(x) __builtin_amdgcn_exp2f(x)
#else
#define EXP2(x) exp2f(x)
#endif

__device__ __forceinline__ u16 f32_to_bf16(float f) {
  u32 u = __float_as_uint(f);
  u32 r = (u + 0x7fffu + ((u >> 16) & 1u)) >> 16;  // RNE
  return (u16)r;
}

__device__ __forceinline__ void gl_lds16(const u16* g, u16* l) {
  __builtin_amdgcn_global_load_lds(
      (const __attribute__((address_space(1))) u32*)g,
      (__attribute__((address_space(3))) u32*)l, 16, 0, 0);
}

// ---- prep: fp32 -> bf16 (RNE) + per-row d = -log2e*sum(xb^2); zero S/cnt ----
__global__ void prep_kernel(const float* __restrict__ x, const float* __restrict__ y,
                            u32* __restrict__ xb, u32* __restrict__ yb,
                            float* __restrict__ da, float* __restrict__ db,
                            u32* __restrict__ Sz) {
  if (blockIdx.x == 0 && threadIdx.x < 4) Sz[threadIdx.x] = 0;  // S[0..2], cnt
  int row = blockIdx.x * 8 + (threadIdx.x >> 5);  // 32 lanes per row
  int l = threadIdx.x & 31;
  const float* src; u32* dst; float* dn; int r;
  if (row < N_PTS) { src = x; dst = xb; dn = da; r = row; }
  else             { src = y; dst = yb; dn = db; r = row - N_PTS; }
  float4 v = ((const float4*)(src + (size_t)r * 128))[l];
  u16 b0 = f32_to_bf16(v.x), b1 = f32_to_bf16(v.y);
  u16 b2 = f32_to_bf16(v.z), b3 = f32_to_bf16(v.w);
  float f0 = __uint_as_float((u32)b0 << 16), f1 = __uint_as_float((u32)b1 << 16);
  float f2 = __uint_as_float((u32)b2 << 16), f3 = __uint_as_float((u32)b3 << 16);
  float p = f0 * f0 + f1 * f1 + f2 * f2 + f3 * f3;
  uint2 pk;
  pk.x = (u32)b0 | ((u32)b1 << 16);
  pk.y = (u32)b2 | ((u32)b3 << 16);
  ((uint2*)(dst + (size_t)r * 64))[l] = pk;
#pragma unroll
  for (int off = 16; off; off >>= 1) p += __shfl_xor(p, off, 64);
  if (l == 0) dn[r] = -LOG2E * p;
}

struct Job { int pair, rr, cc; };

__device__ __forceinline__ Job decode_job(int t) {
  Job jb;
  if (t < 2 * NSELF) {
    jb.pair = (t < NSELF) ? 0 : 1;
    int tt = t - jb.pair * NSELF;
    int r = 0;
    while (tt >= TJ - r) { tt -= TJ - r; r++; }
    jb.rr = r; jb.cc = r + tt;
  } else {
    int q = t - 2 * NSELF;
    jb.pair = 2; jb.rr = q >> 6; jb.cc = q & 63;
  }
  return jb;
}

__device__ __forceinline__ Job next_job(Job c) {
  Job n = c;
  if (c.cc < TJ - 1) { n.cc++; return n; }
  if (c.pair == 2) { n.rr++; n.cc = 0; return n; }
  if (c.rr == TJ - 1) { n.pair = c.pair + 1; n.rr = 0; n.cc = 0; return n; }
  n.rr = c.rr + 1; n.cc = n.rr; return n;
}

__device__ __forceinline__ const u16* selA(int p, const u16* xb, const u16* yb) {
  return (p == 1) ? yb : xb;
}
__device__ __forceinline__ const u16* selB(int p, const u16* xb, const u16* yb) {
  return (p == 0) ? xb : yb;
}

// stage one 64-row x 128-col B panel (16 KB), 4 insts/wave, XOR-chunk swizzle
__device__ __forceinline__ void stage_panel(const u16* gsrc, u16* ldst,
                                            int wid, int q16, int l15) {
#pragma unroll
  for (int q = 0; q < 4; q++) {
    int inst = wid * 4 + q;
    int row = inst * 4 + q16;               // panel row this lane feeds
    int b = l15 ^ (row & 15);               // inverse swizzle on global side
    gl_lds16(gsrc + row * 128 + b * 8, ldst + inst * 512);
  }
}

// A-strip: wave owns 32 rows; afr[ks][m=l31][k=h*8+j]; damMax = max row norm
__device__ __forceinline__ void load_strip(const u16* A, const float* dA, int rr,
                                           int wid, int l31, int h,
                                           short8 afr[8], float& damMax) {
  int rbase = rr * 128 + wid * 32;
#pragma unroll
  for (int ks = 0; ks < 8; ks++)
    afr[ks] = *(const short8*)(A + (size_t)(rbase + l31) * 128 + ks * 16 + h * 8);
  float v = dA[rbase + l31];
#pragma unroll
  for (int off = 16; off; off >>= 1) v = fmaxf(v, __shfl_xor(v, off, 64));
  damMax = v;
}

__global__ __launch_bounds__(256, 4) void mmd_kernel(
    const u16* __restrict__ xb, const u16* __restrict__ yb,
    const float* __restrict__ da, const float* __restrict__ db,
    float* __restrict__ S, u32* __restrict__ cnt, float* __restrict__ out) {
  __shared__ u16 Bt[2][64 * 128];  // 2 x 16 KB ping-pong

  int tid = threadIdx.x;
  int wid = tid >> 6, lane = tid & 63;
  int l31 = lane & 31, h = lane >> 5;
  int q16 = lane >> 4, l15 = lane & 15;

  int start = (blockIdx.x * NJOBS) >> 10;   // NBLOCKS = 1024
  int end = ((blockIdx.x + 1) * NJOBS) >> 10;

  Job jc = decode_job(start);
  int hf = 0;
  short8 afr[8];
  float damMax;
  load_strip(selA(jc.pair, xb, yb), (jc.pair == 1) ? db : da, jc.rr,
             wid, l31, h, afr, damMax);
  stage_panel(selB(jc.pair, xb, yb) + (size_t)jc.cc * 16384, &Bt[0][0],
              wid, q16, l15);
  __syncthreads();

  const float c1 = 2.0f * LOG2E;
  float tsum = 0.f;
  int p = 0;
  int total = 2 * (end - start);

  for (int s = 0; s < total; s++) {
    bool hasNext = (s + 1 < total);
    Job jn = jc;
    if (hf == 1 && hasNext) jn = next_job(jc);

    // dbn for CURRENT sub-panel, issued before next staging so its use never
    // drains the prefetch; sched_barrier pins the order.
    const float* dBc = (jc.pair == 0) ? da : db;
    int cb = jc.cc * 128 + hf * 64;
    float dbn0 = dBc[cb + l31];
    float dbn1 = dBc[cb + 32 + l31];
    __builtin_amdgcn_sched_barrier(0);

    if (hasNext) {
      int npair = (hf == 0) ? jc.pair : jn.pair;
      int ncb = (hf == 0) ? (jc.cc * 128 + 64) : (jn.cc * 128);
      stage_panel(selB(npair, xb, yb) + (size_t)ncb * 128, &Bt[p ^ 1][0],
                  wid, q16, l15);
    }

    // ---- compute: 8 K-steps, 1 A-frag x 2 B-frags ----
    floatx16 acc0, acc1;
#pragma unroll
    for (int i = 0; i < 16; i++) { acc0[i] = 0.f; acc1[i] = 0.f; }

#pragma unroll
    for (int ks = 0; ks < 8; ks++) {
      int c = ks * 2 + h;
      int row0 = l31, row1 = 32 + l31;
      short8 bf0 = *(const short8*)(&Bt[p][row0 * 128 + ((c ^ (row0 & 15)) * 8)]);
      short8 bf1 = *(const short8*)(&Bt[p][row1 * 128 + ((c ^ (row1 & 15)) * 8)]);
      acc0 = __builtin_amdgcn_mfma_f32_32x32x16_bf16(afr[ks], bf0, acc0, 0, 0, 0);
      acc1 = __builtin_amdgcn_mfma_f32_32x32x16_bf16(afr[ks], bf1, acc1, 0, 0, 0);
    }

    // ---- thresholded epilogue ----
    {
      float w = (jc.pair < 2 && jc.rr != jc.cc) ? 2.0f : 1.0f;
      const float* dAc = (jc.pair == 1) ? db : da;
      int rbase = jc.rr * 128 + wid * 32 + 4 * h;
#define DO_FRAG(A_, DBN_)                                                       \
      {                                                                         \
        float mx = (A_)[0];                                                     \
        _Pragma("unroll")                                                       \
        for (int i = 1; i < 16; i++) mx = fmaxf(mx, (A_)[i]);                   \
        if (__any(fmaf(c1, mx, damMax + (DBN_)) > THRESH)) {                    \
          _Pragma("unroll")                                                     \
          for (int r = 0; r < 16; r++) {                                        \
            float dam = dAc[rbase + (r & 3) + 8 * (r >> 2)];                    \
            tsum = fmaf(w, EXP2(fmaf(c1, (A_)[r], dam + (DBN_))), tsum);        \
          }                                                                     \
        }                                                                       \
      }
      DO_FRAG(acc0, dbn0)
      DO_FRAG(acc1, dbn1)
#undef DO_FRAG
    }

    bool pairChange = (hf == 1) && hasNext && (jn.pair != jc.pair);
    if (!hasNext || pairChange) {
      float r = tsum;
#pragma unroll
      for (int off = 32; off; off >>= 1) r += __shfl_down(r, off, 64);
      if (lane == 0) atomicAdd(&S[jc.pair], r);
      tsum = 0.f;
    }
    if (hf == 1 && hasNext && (jn.pair != jc.pair || jn.rr != jc.rr))
      load_strip(selA(jn.pair, xb, yb), (jn.pair == 1) ? db : da, jn.rr,
                 wid, l31, h, afr, damMax);

    __syncthreads();
    p ^= 1;
    if (hf == 1) jc = jn;
    hf ^= 1;
  }

  // ---- last finishing wave combines ----
  if (lane == 0) {
    __threadfence();
    u32 old = atomicAdd(cnt, 1u);
    if (old == (u32)(NWAVES - 1)) {
      float s0 = atomicAdd(&S[0], 0.0f);
      float s1 = atomicAdd(&S[1], 0.0f);
      float s2 = atomicAdd(&S[2], 0.0f);
      out[0] = (s0 + s1 - 2.0f * s2) * (1.0f / ((float)N_PTS * (float)N_PTS));
    }
  }
}

extern "C" void kernel_launch(void* const* d_in, const int* in_sizes, int n_in,
                              void* d_out, int out_size, void* d_ws, size_t ws_size,
                              hipStream_t stream) {
  const float* x = (const float*)d_in[0];
  const float* y = (const float*)d_in[1];
  char* ws = (char*)d_ws;
  float* S = (float*)ws;                                   // S[0..2], cnt
  u32* cnt = (u32*)ws + 3;
  u32* xb = (u32*)(ws + 256);                              // 2 MB bf16
  u32* yb = (u32*)(ws + 256 + 2097152);                    // 2 MB bf16
  float* da = (float*)(ws + 256 + 2 * 2097152);            // 32 KB
  float* db = (float*)(ws + 256 + 2 * 2097152 + 32768);    // 32 KB

  prep_kernel<<<2048, 256, 0, stream>>>(x, y, xb, yb, da, db, (u32*)ws);
  mmd_kernel<<<NBLOCKS, 256, 0, stream>>>((const u16*)xb, (const u16*)yb,
                                          da, db, S, cnt, (float*)d_out);
}

// Round 6
// 174.109 us; speedup vs baseline: 1.1092x; 1.1092x over previous
//
#include <hip/hip_runtime.h>

// MMD RBF loss, N=8192, D=128, gamma=1, fp32 in, fp32 scalar out.
// R6: fragment-layout-in-memory. Prep emits bf16 in MFMA-ready chunk order:
// 16-B chunk of (row r, k-chunk c) at uint4 index (r>>5)*512 + c*32 + (r&31).
// One wave-load = 64 lanes x 16 B contiguous = 1 KB, perfectly coalesced,
// for BOTH A-frags and B-frags. Hot kernel: no LDS, no barriers, no staging.
// 4 waves/block share one 128x128 job (same B addresses -> L1 broadcast).
// 32x32x16 bf16 MFMA, 4 independent acc chains. Thresholded exp epilogue.

#define N_PTS 8192
#define TJ 64          // 8192/128 tiles per side
#define NSELF 2080     // 64*65/2
#define NJOBS 8256     // 2*2080 + 4096
#define NBLOCKS 768
#define NWAVES (NBLOCKS * 4)
#define LOG2E 1.4426950408889634f
#define THRESH -40.0f

typedef __attribute__((ext_vector_type(8))) short short8;    // 8 bf16 = 16 B
typedef __attribute__((ext_vector_type(16))) float floatx16; // 32x32 acc
typedef unsigned int u32;
typedef unsigned short u16;

#if __has_builtin(__builtin_amdgcn_exp2f)
#define EXP2(x) __builtin_amdgcn_exp2f(x)
#else
#define EXP2(x) exp2f(x)
#endif

__device__ __forceinline__ u16 f32_to_bf16(float f) {
  u32 u = __float_as_uint(f);
  u32 r = (u + 0x7fffu + ((u >> 16) & 1u)) >> 16;  // RNE
  return (u16)r;
}

// ---- prep: fp32 -> bf16 chunks in MFMA-ready layout + row norms ----
// grid 512 x 256. Block rb handles 32 source rows (rb*32..+31).
// Thread t: rl = t&31, handles k-chunks c0 = t>>5 and c0+8.
__global__ void prep_kernel(const float* __restrict__ x, const float* __restrict__ y,
                            uint4* __restrict__ xb, uint4* __restrict__ yb,
                            float* __restrict__ da, float* __restrict__ db,
                            u32* __restrict__ Sz) {
  __shared__ float part[256];
  int rb = blockIdx.x;
  int t = threadIdx.x;
  if (rb == 0 && t < 4) Sz[t] = 0;  // S[0..2], cnt
  int rl = t & 31, c0 = t >> 5;
  const float* src; uint4* dst; float* dn; int rb_loc;
  if (rb < 256) { src = x; dst = xb; dn = da; rb_loc = rb; }
  else          { src = y; dst = yb; dn = db; rb_loc = rb - 256; }
  const float* rowp = src + (size_t)(rb_loc * 32 + rl) * 128;
  float s = 0.f;
#pragma unroll
  for (int i = 0; i < 2; i++) {
    int c = c0 + i * 8;
    float4 v0 = *(const float4*)(rowp + c * 8);
    float4 v1 = *(const float4*)(rowp + c * 8 + 4);
    u16 b0 = f32_to_bf16(v0.x), b1 = f32_to_bf16(v0.y);
    u16 b2 = f32_to_bf16(v0.z), b3 = f32_to_bf16(v0.w);
    u16 b4 = f32_to_bf16(v1.x), b5 = f32_to_bf16(v1.y);
    u16 b6 = f32_to_bf16(v1.z), b7 = f32_to_bf16(v1.w);
#define SQ(b) { float f = __uint_as_float((u32)(b) << 16); s = fmaf(f, f, s); }
    SQ(b0) SQ(b1) SQ(b2) SQ(b3) SQ(b4) SQ(b5) SQ(b6) SQ(b7)
#undef SQ
    uint4 pk;
    pk.x = (u32)b0 | ((u32)b1 << 16);
    pk.y = (u32)b2 | ((u32)b3 << 16);
    pk.z = (u32)b4 | ((u32)b5 << 16);
    pk.w = (u32)b6 | ((u32)b7 << 16);
    dst[(size_t)rb_loc * 512 + c * 32 + rl] = pk;
  }
  part[t] = s;
  __syncthreads();
  if (t < 32) {
    float v = 0.f;
#pragma unroll
    for (int c = 0; c < 8; c++) v += part[c * 32 + t];
    dn[rb_loc * 32 + t] = -LOG2E * v;
  }
}

struct Job { int pair, rr, cc; };

__device__ __forceinline__ Job decode_job(int t) {
  Job jb;
  if (t < 2 * NSELF) {
    jb.pair = (t < NSELF) ? 0 : 1;
    int tt = t - jb.pair * NSELF;
    int r = 0;
    while (tt >= TJ - r) { tt -= TJ - r; r++; }
    jb.rr = r; jb.cc = r + tt;
  } else {
    int q = t - 2 * NSELF;
    jb.pair = 2; jb.rr = q >> 6; jb.cc = q & 63;
  }
  return jb;
}

__device__ __forceinline__ Job next_job(Job c) {
  Job n = c;
  if (c.cc < TJ - 1) { n.cc++; return n; }
  if (c.pair == 2) { n.rr++; n.cc = 0; return n; }
  if (c.rr == TJ - 1) { n.pair = c.pair + 1; n.rr = 0; n.cc = 0; return n; }
  n.rr = c.rr + 1; n.cc = n.rr; return n;
}

__device__ __forceinline__ const uint4* selA(int p, const uint4* xb, const uint4* yb) {
  return (p == 1) ? yb : xb;
}
__device__ __forceinline__ const uint4* selB(int p, const uint4* xb, const uint4* yb) {
  return (p == 0) ? xb : yb;
}

// A-strip: wave owns 32 rows (rb32 = rr*4 + wid); afr[ks] one coalesced 1 KB load
__device__ __forceinline__ void load_strip(const uint4* A, const float* dA,
                                           int rr, int wid, int lane,
                                           short8 afr[8], float& damMax) {
  int rb32 = rr * 4 + wid;
  const uint4* base = A + (size_t)rb32 * 512 + lane;
#pragma unroll
  for (int ks = 0; ks < 8; ks++)
    afr[ks] = *(const short8*)(base + ks * 64);
  float v = dA[rb32 * 32 + (lane & 31)];
#pragma unroll
  for (int off = 32; off; off >>= 1) v = fmaxf(v, __shfl_xor(v, off, 64));
  damMax = v;
}

__global__ __launch_bounds__(256, 3) void mmd_kernel(
    const uint4* __restrict__ xb, const uint4* __restrict__ yb,
    const float* __restrict__ da, const float* __restrict__ db,
    float* __restrict__ S, u32* __restrict__ cnt, float* __restrict__ out) {
  int tid = threadIdx.x;
  int wid = tid >> 6, lane = tid & 63;
  int l31 = lane & 31, h = lane >> 5;

  int start = (int)(((long)blockIdx.x * NJOBS) / NBLOCKS);
  int end = (int)(((long)(blockIdx.x + 1) * NJOBS) / NBLOCKS);

  Job jc = decode_job(start);
  short8 afr[8];
  float damMax;
  load_strip(selA(jc.pair, xb, yb), (jc.pair == 1) ? db : da, jc.rr,
             wid, lane, afr, damMax);

  // preload bf[0] for first job's ks=0 (4 n-groups)
  short8 bf[2][4];
  {
    const uint4* Bp = selB(jc.pair, xb, yb) + (size_t)jc.cc * 2048 + lane;
#pragma unroll
    for (int ng = 0; ng < 4; ng++)
      bf[0][ng] = *(const short8*)(Bp + ng * 512);
  }

  const float c1 = 2.0f * LOG2E;
  float tsum = 0.f;

  for (int j = start; j < end; j++) {
    bool hasNext = (j + 1 < end);
    Job jn = hasNext ? next_job(jc) : jc;

    // exact per-lane col norms for current job (used ~600 cyc later)
    const float* dBc = (jc.pair == 0) ? da : db;
    float dbn[4];
#pragma unroll
    for (int ng = 0; ng < 4; ng++) dbn[ng] = dBc[jc.cc * 128 + ng * 32 + l31];

    const uint4* Bp = selB(jc.pair, xb, yb) + (size_t)jc.cc * 2048 + lane;
    const uint4* Bn = selB(jn.pair, xb, yb) + (size_t)jn.cc * 2048 + lane;

    floatx16 acc[4];
#pragma unroll
    for (int ng = 0; ng < 4; ng++)
#pragma unroll
      for (int i = 0; i < 16; i++) acc[ng][i] = 0.f;

#pragma unroll
    for (int ks = 0; ks < 8; ks++) {
      int pn = (ks + 1) & 1;
      const uint4* src = (ks < 7) ? (Bp + (ks + 1) * 64) : Bn;  // next job ks=0
#pragma unroll
      for (int ng = 0; ng < 4; ng++)
        bf[pn][ng] = *(const short8*)(src + ng * 512);
      int pc = ks & 1;
#pragma unroll
      for (int ng = 0; ng < 4; ng++)
        acc[ng] = __builtin_amdgcn_mfma_f32_32x32x16_bf16(afr[ks], bf[pc][ng],
                                                          acc[ng], 0, 0, 0);
    }

    // ---- thresholded epilogue (exact exp path only near the diagonal) ----
    {
      float w = (jc.pair < 2 && jc.rr != jc.cc) ? 2.0f : 1.0f;
      const float* dAc = (jc.pair == 1) ? db : da;
      int rbase = (jc.rr * 4 + wid) * 32 + 4 * h;
#pragma unroll
      for (int ng = 0; ng < 4; ng++) {
        float mx = acc[ng][0];
#pragma unroll
        for (int i = 1; i < 16; i++) mx = fmaxf(mx, acc[ng][i]);
        if (__any(fmaf(c1, mx, damMax + dbn[ng]) > THRESH)) {
#pragma unroll
          for (int r = 0; r < 16; r++) {
            float dam = dAc[rbase + (r & 3) + 8 * (r >> 2)];
            tsum = fmaf(w, EXP2(fmaf(c1, acc[ng][r], dam + dbn[ng])), tsum);
          }
        }
      }
    }

    bool pairChange = hasNext && (jn.pair != jc.pair);
    if (!hasNext || pairChange) {
      float r = tsum;
#pragma unroll
      for (int off = 32; off; off >>= 1) r += __shfl_down(r, off, 64);
      if (lane == 0) atomicAdd(&S[jc.pair], r);
      tsum = 0.f;
    }
    if (hasNext && (pairChange || jn.rr != jc.rr))
      load_strip(selA(jn.pair, xb, yb), (jn.pair == 1) ? db : da, jn.rr,
                 wid, lane, afr, damMax);
    jc = jn;
  }

  // ---- last finishing wave combines ----
  if (lane == 0) {
    __threadfence();
    u32 old = atomicAdd(cnt, 1u);
    if (old == (u32)(NWAVES - 1)) {
      float s0 = atomicAdd(&S[0], 0.0f);
      float s1 = atomicAdd(&S[1], 0.0f);
      float s2 = atomicAdd(&S[2], 0.0f);
      out[0] = (s0 + s1 - 2.0f * s2) * (1.0f / ((float)N_PTS * (float)N_PTS));
    }
  }
}

extern "C" void kernel_launch(void* const* d_in, const int* in_sizes, int n_in,
                              void* d_out, int out_size, void* d_ws, size_t ws_size,
                              hipStream_t stream) {
  const float* x = (const float*)d_in[0];
  const float* y = (const float*)d_in[1];
  char* ws = (char*)d_ws;
  float* S = (float*)ws;                                   // S[0..2], cnt
  u32* cnt = (u32*)ws + 3;
  uint4* xb = (uint4*)(ws + 256);                          // 2 MB bf16 chunks
  uint4* yb = (uint4*)(ws + 256 + 2097152);                // 2 MB bf16 chunks
  float* da = (float*)(ws + 256 + 2 * 2097152);            // 32 KB
  float* db = (float*)(ws + 256 + 2 * 2097152 + 32768);    // 32 KB

  prep_kernel<<<512, 256, 0, stream>>>(x, y, xb, yb, da, db, (u32*)ws);
  mmd_kernel<<<NBLOCKS, 256, 0, stream>>>(xb, yb, da, db, S, cnt, (float*)d_out);
}

// Round 7
// 146.678 us; speedup vs baseline: 1.3166x; 1.1870x over previous
//
#include <hip/hip_runtime.h>

// MMD RBF loss, N=8192, D=128, gamma=1, fp32 in, fp32 scalar out.
// R7: norms folded into MFMA via K extension 128->144.
//   A-form row: [-sqrt2*xb | h,m,l,1,1,1,0..0]   (h+m+l = 3-term bf16 split of |xb|^2)
//   B-form row: [+sqrt2*xb | 1,1,1,h,m,l,0..0]
//   => MFMA acc = |x_i|^2 + |x_j|^2 - 2 x_i.x_j = dist_ij directly (fp32).
// Hot loop has ZERO vmem loads except global_load_lds staging (linear 36 KB
// copy, fragment-layout in memory) -> the vmcnt(0)+s_barrier pipeline is
// clean: stage j+1 issued right after the barrier, never drained mid-job.
// Epilogue: pure register VALU; exp2 only on frags with min(dist) < 25.

#define N_PTS 8192
#define TJ 64            // 8192/128 tiles per side
#define NSELF 2080       // 64*65/2
#define NJOBS 8256       // 2*2080 + 4096
#define NBLOCKS 512
#define NWAVES (NBLOCKS * 4)
#define C2 (-1.4426950408889634f)   // -gamma*log2(e)
#define TMIN 25.0f                  // skip frag if min dist > 25 (2^-36 mass)
#define RB_U4 576        // uint4 per 32-row block: 9 chunks * 64
#define TILE_U4 2304     // 128-row tile: 4 * RB_U4 (contiguous!)
#define SQRT2 1.41421356237309515f
#define ONEB 0x3F80u

typedef __attribute__((ext_vector_type(8))) short short8;    // 8 bf16 = 16 B
typedef __attribute__((ext_vector_type(16))) float floatx16; // 32x32 acc
typedef unsigned int u32;
typedef unsigned short u16;

#if __has_builtin(__builtin_amdgcn_exp2f)
#define EXP2(x) __builtin_amdgcn_exp2f(x)
#else
#define EXP2(x) exp2f(x)
#endif

__device__ __forceinline__ u16 f32_to_bf16(float f) {
  u32 u = __float_as_uint(f);
  u32 r = (u + 0x7fffu + ((u >> 16) & 1u)) >> 16;  // RNE
  return (u16)r;
}
__device__ __forceinline__ float bf_to_f32(u16 b) {
  return __uint_as_float((u32)b << 16);
}

__device__ __forceinline__ void gl_lds16(const uint4* g, u16* l) {
  __builtin_amdgcn_global_load_lds(
      (const __attribute__((address_space(1))) u32*)g,
      (__attribute__((address_space(3))) u32*)l, 16, 0, 0);
}

// ---- prep: build A-form / B-form fragment-layout buffers ----
// grid 512: block b -> matrix (b>>8), 32-row block rb (b&255).
// thread t: row rl = t&31, slot-group u = t>>5; slots s = u, u+8 (cols 8s..8s+7).
__global__ void prep_kernel(const float* __restrict__ x, const float* __restrict__ y,
                            uint4* __restrict__ XA, uint4* __restrict__ XB,
                            uint4* __restrict__ YA, uint4* __restrict__ YB,
                            u32* __restrict__ Sz) {
  __shared__ float part[32][8];
  int b = blockIdx.x, t = threadIdx.x;
  if (b == 0 && t < 4) Sz[t] = 0;  // S[0..2], cnt
  int which = b >> 8, rb = b & 255;
  const float* src = which ? y : x;
  uint4* FA = which ? YA : XA;
  uint4* FB = which ? YB : XB;
  int rl = t & 31, u = t >> 5;
  const float* rowp = src + (size_t)(rb * 32 + rl) * 128;
  float ssum = 0.f;
  uint4 pk[2];
#pragma unroll
  for (int i = 0; i < 2; i++) {
    int s = u + i * 8;  // slot 0..15 covers cols 8s..8s+7
    float4 v0 = *(const float4*)(rowp + s * 8);
    float4 v1 = *(const float4*)(rowp + s * 8 + 4);
    u16 b0 = f32_to_bf16(SQRT2 * v0.x), b1 = f32_to_bf16(SQRT2 * v0.y);
    u16 b2 = f32_to_bf16(SQRT2 * v0.z), b3 = f32_to_bf16(SQRT2 * v0.w);
    u16 b4 = f32_to_bf16(SQRT2 * v1.x), b5 = f32_to_bf16(SQRT2 * v1.y);
    u16 b6 = f32_to_bf16(SQRT2 * v1.z), b7 = f32_to_bf16(SQRT2 * v1.w);
#define SQ(bb) { float f = bf_to_f32(bb); ssum = fmaf(f, f, ssum); }
    SQ(b0) SQ(b1) SQ(b2) SQ(b3) SQ(b4) SQ(b5) SQ(b6) SQ(b7)
#undef SQ
    pk[i].x = (u32)b0 | ((u32)b1 << 16);
    pk[i].y = (u32)b2 | ((u32)b3 << 16);
    pk[i].z = (u32)b4 | ((u32)b5 << 16);
    pk[i].w = (u32)b6 | ((u32)b7 << 16);
  }
#pragma unroll
  for (int i = 0; i < 2; i++) {
    int s = u + i * 8;
    size_t idx = (size_t)(rb * 9 + (s >> 1)) * 64 + (s & 1) * 32 + rl;
    FB[idx] = pk[i];
    uint4 neg;
    neg.x = pk[i].x ^ 0x80008000u; neg.y = pk[i].y ^ 0x80008000u;
    neg.z = pk[i].z ^ 0x80008000u; neg.w = pk[i].w ^ 0x80008000u;
    FA[idx] = neg;
  }
  part[rl][u] = ssum;
  __syncthreads();
  if (t < 32) {
    float nsum = 0.f;
#pragma unroll
    for (int k = 0; k < 8; k++) nsum += part[t][k];
    float n = 0.5f * nsum;                    // |xb|^2 from stored bf16 values
    u16 h = f32_to_bf16(n);  float r1 = n - bf_to_f32(h);
    u16 m = f32_to_bf16(r1); float r2 = r1 - bf_to_f32(m);
    u16 l = f32_to_bf16(r2);
    uint4 a8, b8;
    a8.x = (u32)h | ((u32)m << 16); a8.y = (u32)l | (ONEB << 16);
    a8.z = ONEB | (ONEB << 16);     a8.w = 0;
    b8.x = ONEB | (ONEB << 16);     b8.y = ONEB | ((u32)h << 16);
    b8.z = (u32)m | ((u32)l << 16); b8.w = 0;
    size_t idx = (size_t)(rb * 9 + 8) * 64 + t;   // half 0
    FA[idx] = a8; FB[idx] = b8;
  } else if (t < 64) {
    uint4 z = {0, 0, 0, 0};
    size_t idx = (size_t)(rb * 9 + 8) * 64 + t;   // half 1: cols 136..143 = 0
    FA[idx] = z; FB[idx] = z;
  }
}

struct Job { int pair, rr, cc; };

__device__ __forceinline__ Job decode_job(int t) {
  Job jb;
  if (t < 2 * NSELF) {
    jb.pair = (t < NSELF) ? 0 : 1;
    int tt = t - jb.pair * NSELF;
    int r = 0;
    while (tt >= TJ - r) { tt -= TJ - r; r++; }
    jb.rr = r; jb.cc = r + tt;
  } else {
    int q = t - 2 * NSELF;
    jb.pair = 2; jb.rr = q >> 6; jb.cc = q & 63;
  }
  return jb;
}

__device__ __forceinline__ Job next_job(Job c) {
  Job n = c;
  if (c.cc < TJ - 1) { n.cc++; return n; }
  if (c.pair == 2) { n.rr++; n.cc = 0; return n; }
  if (c.rr == TJ - 1) { n.pair = c.pair + 1; n.rr = 0; n.cc = 0; return n; }
  n.rr = c.rr + 1; n.cc = n.rr; return n;
}

// linear 36 KB tile copy: 36 insts, wave w does i = k*4+w
__device__ __forceinline__ void stage_tile(const uint4* B, int cc, u16* lds,
                                           int wid, int lane) {
  const uint4* src = B + (size_t)cc * TILE_U4 + lane;
#pragma unroll
  for (int k = 0; k < 9; k++) {
    int i = k * 4 + wid;
    gl_lds16(src + i * 64, lds + i * 512);
  }
}

__device__ __forceinline__ void load_afr(const uint4* A, int rr, int wid, int lane,
                                         short8 afr[9]) {
  const uint4* base = A + (size_t)(rr * 4 + wid) * RB_U4 + lane;
#pragma unroll
  for (int ks = 0; ks < 9; ks++)
    afr[ks] = *(const short8*)(base + ks * 64);
}

__global__ __launch_bounds__(256, 2) void mmd_kernel(
    const uint4* __restrict__ XA, const uint4* __restrict__ XB,
    const uint4* __restrict__ YA, const uint4* __restrict__ YB,
    float* __restrict__ S, u32* __restrict__ cnt, float* __restrict__ out) {
  __shared__ u16 Bt[2][TILE_U4 * 8];  // 2 x 36 KB

  int tid = threadIdx.x;
  int wid = tid >> 6, lane = tid & 63;

  int start = (blockIdx.x * NJOBS) >> 9;
  int end = ((blockIdx.x + 1) * NJOBS) >> 9;

  Job jc = decode_job(start);
  const uint4* fA = (jc.pair == 1) ? YA : XA;
  const uint4* fB = (jc.pair == 0) ? XB : YB;

  short8 afr[9];
  load_afr(fA, jc.rr, wid, lane, afr);
  stage_tile(fB, jc.cc, &Bt[0][0], wid, lane);

  float tsum = 0.f;
  int p = 0;

  for (int j = start; j < end; j++) {
    bool hasNext = (j + 1 < end);
    Job jn = hasNext ? next_job(jc) : jc;
    const uint4* nA = (jn.pair == 1) ? YA : XA;
    const uint4* nB = (jn.pair == 0) ? XB : YB;

    // stage j landed >= one full job ago; raw barrier; prefetch j+1.
    __builtin_amdgcn_s_waitcnt(0x0F70);  // vmcnt(0) only
    __asm__ __volatile__("" ::: "memory");
    __builtin_amdgcn_s_barrier();
    __asm__ __volatile__("" ::: "memory");
    if (hasNext) stage_tile(nB, jn.cc, &Bt[p ^ 1][0], wid, lane);

    // ---- compute: 9 K-steps x 4 n-groups; acc = dist directly ----
    floatx16 acc[4];
#pragma unroll
    for (int ng = 0; ng < 4; ng++)
#pragma unroll
      for (int i = 0; i < 16; i++) acc[ng][i] = 0.f;

#pragma unroll
    for (int ks = 0; ks < 9; ks++) {
      short8 bf[4];
#pragma unroll
      for (int ng = 0; ng < 4; ng++)
        bf[ng] = *(const short8*)(&Bt[p][((ng * 9 + ks) * 64 + lane) * 8]);
#pragma unroll
      for (int ng = 0; ng < 4; ng++)
        acc[ng] = __builtin_amdgcn_mfma_f32_32x32x16_bf16(afr[ks], bf[ng],
                                                          acc[ng], 0, 0, 0);
    }

    // ---- epilogue: pure register VALU; exp2 only near the diagonal ----
    {
      float w = (jc.pair < 2 && jc.rr != jc.cc) ? 2.0f : 1.0f;
#pragma unroll
      for (int ng = 0; ng < 4; ng++) {
        float mn = acc[ng][0];
#pragma unroll
        for (int i = 1; i < 16; i++) mn = fminf(mn, acc[ng][i]);
        if (__any(mn < TMIN)) {
#pragma unroll
          for (int r = 0; r < 16; r++)
            tsum = fmaf(w, EXP2(C2 * acc[ng][r]), tsum);
        }
      }
    }

    bool pairChange = hasNext && (jn.pair != jc.pair);
    if (!hasNext || pairChange) {
      float r = tsum;
#pragma unroll
      for (int off = 32; off; off >>= 1) r += __shfl_down(r, off, 64);
      if (lane == 0) atomicAdd(&S[jc.pair], r);
      tsum = 0.f;
    }
    // strip change: reload A-frags (rare; current job's MFMAs already done)
    if (hasNext && (pairChange || jn.rr != jc.rr))
      load_afr(nA, jn.rr, wid, lane, afr);

    p ^= 1;
    jc = jn;
  }

  // ---- last finishing wave combines ----
  if (lane == 0) {
    __threadfence();
    u32 old = atomicAdd(cnt, 1u);
    if (old == (u32)(NWAVES - 1)) {
      float s0 = atomicAdd(&S[0], 0.0f);
      float s1 = atomicAdd(&S[1], 0.0f);
      float s2 = atomicAdd(&S[2], 0.0f);
      out[0] = (s0 + s1 - 2.0f * s2) * (1.0f / ((float)N_PTS * (float)N_PTS));
    }
  }
}

extern "C" void kernel_launch(void* const* d_in, const int* in_sizes, int n_in,
                              void* d_out, int out_size, void* d_ws, size_t ws_size,
                              hipStream_t stream) {
  const float* x = (const float*)d_in[0];
  const float* y = (const float*)d_in[1];
  char* ws = (char*)d_ws;
  float* S = (float*)ws;                                   // S[0..2], cnt
  u32* cnt = (u32*)ws + 3;
  const size_t FB_BYTES = (size_t)256 * RB_U4 * 16;        // 2.359 MB per form
  uint4* XA = (uint4*)(ws + 256);
  uint4* XB = (uint4*)(ws + 256 + FB_BYTES);
  uint4* YA = (uint4*)(ws + 256 + 2 * FB_BYTES);
  uint4* YB = (uint4*)(ws + 256 + 3 * FB_BYTES);

  prep_kernel<<<512, 256, 0, stream>>>(x, y, XA, XB, YA, YB, (u32*)ws);
  mmd_kernel<<<NBLOCKS, 256, 0, stream>>>(XA, XB, YA, YB, S, cnt, (float*)d_out);
}